// Round 9
// baseline (69.552 us; speedup 1.0000x reference)
//
#include <hip/hip_runtime.h>
#include <hip/hip_bf16.h>

typedef int v4i __attribute__((ext_vector_type(4)));

// Padded quantized activations: qp[n][hp][wp][c], hp,wp in [0,114), c in [0,64)
#define QP_N 32
#define QP_HP 114
#define QP_WP 114
#define QP_C 64
#define QP_ROW (QP_WP * QP_C)                            // 7296 B per padded row
#define QP_BYTES ((size_t)QP_N * QP_HP * QP_WP * QP_C)   // 26,615,808

#define QBLOCKS (QP_N * QP_HP)      // 3648 quantize blocks
#define PBLOCKS 9                   // prepack blocks folded into same launch

// XCD pinning: blockIdx round-robins across 8 XCDs. Both kernels remap
// blockIdx bijectively so every block of image n satisfies blockIdx % 8 ==
// n % 8: quantize blocks WRITE image n's qp rows on the same XCD where conv
// blocks READ them. Per-XCD qp working set = 4 images * 832 KB = 3.3 MB <
// 4 MB L2. NO nontemporal hints (r4-r6: NT cost +5-7us every time).

// ---------------------------------------------------------------------------
// Kernel 1: quantize + NCHW -> padded NHWC int8 transpose, with border zeroing.
// Physical blocks [0, 3648): p = ((n>>3)*114 + hp)*8 + (n&7)  (bijective).
// hp==0/113 -> zero row. Else transpose row h=hp-1 through LDS and zero the
// wp=0 / wp=113 columns.
// Blocks [3648, 3657): weight prepack into MFMA B-fragment layout.
//   wb[frag][lane][16B], frag = (kh*3+kw)*4 + g.
//   B-frag (K=ci x N=co): lane l holds B[k=(l>>4)*16+j][n = l&15], j=0..15.
//   co = g*16 + (l&15), ci = (l>>4)*16 + j.  qw arrives widened to int32.
// ---------------------------------------------------------------------------
__global__ __launch_bounds__(256) void quantize_kernel(const float* __restrict__ x,
                                                       signed char* __restrict__ qp,
                                                       const int* __restrict__ qw,
                                                       signed char* __restrict__ wb) {
    int t = threadIdx.x;

    if (blockIdx.x >= QBLOCKS) {
        // ---- prepack path ----
        int idx = (blockIdx.x - QBLOCKS) * 256 + t;
        if (idx >= 36 * 64) return;
        int lane = idx & 63;
        int frag = idx >> 6;             // 0..35
        int g = frag & 3;
        int tap = frag >> 2;             // kh*3+kw
        int kh = tap / 3;
        int kw = tap - kh * 3;
        int co = g * 16 + (lane & 15);
        int cibase = (lane >> 4) * 16;
        int dwv[4];
#pragma unroll
        for (int d = 0; d < 4; ++d) {
            int acc = 0;
#pragma unroll
            for (int b = 0; b < 4; ++b) {
                int ci = cibase + d * 4 + b;
                int v = qw[((co * 64 + ci) * 3 + kh) * 3 + kw];
                acc |= (v & 0xff) << (8 * b);
            }
            dwv[d] = acc;
        }
        *reinterpret_cast<int4*>(wb + (size_t)idx * 16) = make_int4(dwv[0], dwv[1], dwv[2], dwv[3]);
        return;
    }

    // XCD-pinned index decode: p = ((n>>3)*114 + hp)*8 + (n&7)
    int p = blockIdx.x;
    int res = p & 7;
    int r = p >> 3;                 // 0..455
    int gq = r / 114;               // n>>3 in 0..3
    int hp = r - gq * 114;
    int n = gq * 8 + res;

    signed char* rowbase = qp + ((size_t)n * QP_HP + hp) * QP_ROW;

    if (hp == 0 || hp == QP_HP - 1) {
        // zero the whole padded row: 114*64 = 7296 B = 228 * 32B
        if (t < 228) {
            int4 z = make_int4(0, 0, 0, 0);
            int4* dst = reinterpret_cast<int4*>(rowbase + t * 32);
            dst[0] = z;
            dst[1] = z;
        }
        return;
    }

    int h = hp - 1;
    __shared__ float lds[64][112];

    const float* xp = x + (size_t)n * 64 * 12544 + h * 112;  // x[n][c][h][w], c-plane stride 12544
#pragma unroll
    for (int j = 0; j < 7; ++j) {
        int fidx = j * 256 + t;      // 1792 float4 chunks total (64 rows * 28)
        int c = fidx / 28;
        int f = fidx - c * 28;
        float4 v = *reinterpret_cast<const float4*>(xp + (size_t)c * 12544 + f * 4);
        *reinterpret_cast<float4*>(&lds[c][f * 4]) = v;
    }
    __syncthreads();

    if (t < 224) {
        int w = t >> 1;              // 0..111
        int ch = (t & 1) * 32;       // channel half: 0 or 32
        int dw[8];
#pragma unroll
        for (int q = 0; q < 8; ++q) {
            int d = 0;
#pragma unroll
            for (int b = 0; b < 4; ++b) {
                float v = lds[ch + q * 4 + b][w];
                float s = rintf(v * 20.0f);                 // round-half-to-even, matches jnp.round
                s = fminf(127.0f, fmaxf(-128.0f, s));
                int iv = (int)s;
                d |= (iv & 0xff) << (8 * b);
            }
            dw[q] = d;
        }
        int4* dst = reinterpret_cast<int4*>(rowbase + (size_t)(w + 1) * QP_C + ch);
        dst[0] = make_int4(dw[0], dw[1], dw[2], dw[3]);
        dst[1] = make_int4(dw[4], dw[5], dw[6], dw[7]);
    } else if (t < 232) {
        // zero border columns wp=0 and wp=113 (64 B each = 4 int4 each)
        int i = t - 224;
        int col = (i >> 2) ? (QP_WP - 1) : 0;
        int part = i & 3;
        *reinterpret_cast<int4*>(rowbase + (size_t)col * QP_C + part * 16) = make_int4(0, 0, 0, 0);
    }
}

// ---------------------------------------------------------------------------
// Kernel 2: implicit-GEMM conv, A = activations (M=16 px), B = weights (N=16 co).
// CO-SPLIT for occupancy: each 256-thr block computes only 32 of 64 output
// channels (chalf), staging 18 frags = 18.4 KB LDS (vs 36.9) -> LDS allows
// 8 blocks/CU; acc halves to 32 AGPRs -> __launch_bounds__(256,6) = 24
// waves/CU (vs 16). qp reads double but stay L2-local (XCD pin; paired
// chalf=0/1 blocks read identical qp rows back-to-back).
//   A-frag: lane l reads qp[n][h+kh][w0+pb*16+kw + (l&15)][(l>>4)*16 ..+16]
//   D-frag (pb,g): co = chalf*32 + g*16 + (l&15), px (l>>4)*4..+3 -> float4
// ---------------------------------------------------------------------------
template <int NPB>
__device__ __forceinline__ void conv_tile(const signed char* __restrict__ abase,
                                          const signed char* wl,
                                          const int* __restrict__ bias,
                                          const float* __restrict__ deq,
                                          float* __restrict__ outp,
                                          int lane, int cobase) {
    v4i acc[NPB][2];
#pragma unroll
    for (int pb = 0; pb < NPB; ++pb)
#pragma unroll
        for (int g = 0; g < 2; ++g)
            acc[pb][g] = (v4i){0, 0, 0, 0};

#pragma unroll
    for (int kh = 0; kh < 3; ++kh) {
        const signed char* arow = abase + (size_t)kh * QP_ROW;
#pragma unroll
        for (int kw = 0; kw < 3; ++kw) {
            v4i w0f = *reinterpret_cast<const v4i*>(wl + (size_t)(((kh * 3 + kw) * 2 + 0)) * 1024);
            v4i w1f = *reinterpret_cast<const v4i*>(wl + (size_t)(((kh * 3 + kw) * 2 + 1)) * 1024);
#pragma unroll
            for (int pb = 0; pb < NPB; ++pb) {
                v4i af = *reinterpret_cast<const v4i*>(arow + (size_t)(pb * 16 + kw) * QP_C);
                acc[pb][0] = __builtin_amdgcn_mfma_i32_16x16x64_i8(af, w0f, acc[pb][0], 0, 0, 0);
                acc[pb][1] = __builtin_amdgcn_mfma_i32_16x16x64_i8(af, w1f, acc[pb][1], 0, 0, 0);
            }
        }
    }

    int cbase = lane & 15;           // co within group
    int pq = (lane >> 4) * 4;        // pixel quad start within 16-px block
#pragma unroll
    for (int g = 0; g < 2; ++g) {
        int co = cobase + g * 16 + cbase;
        int bv = bias[co];
        float dv = deq[co];
        float* orow = outp + (size_t)co * 12544 + pq;
#pragma unroll
        for (int pb = 0; pb < NPB; ++pb) {
            float4 v;
            v.x = (float)(acc[pb][g][0] + bv) * dv;
            v.y = (float)(acc[pb][g][1] + bv) * dv;
            v.z = (float)(acc[pb][g][2] + bv) * dv;
            v.w = (float)(acc[pb][g][3] + bv) * dv;
            *reinterpret_cast<float4*>(orow + pb * 16) = v;
        }
    }
}

__global__ __launch_bounds__(256, 6) void conv_kernel(const signed char* __restrict__ qp,
                                                      const signed char* __restrict__ wb,
                                                      const int* __restrict__ bias,
                                                      const float* __restrict__ deq,
                                                      float* __restrict__ out) {
    __shared__ signed char wlds[18432];      // 18 frags (this chalf) * 1024 B
    int t = threadIdx.x;

    // XCD-pinned decode: p = ((n>>3)*112 + k*2 + chalf)*8 + (n&7)
    int p = blockIdx.x;              // 0..3583
    int res = p & 7;
    int s = p >> 3;                  // 0..447
    int gq = s / 112;                // n>>3
    int rem = s - gq * 112;          // 0..111
    int k = rem >> 1;                // 0..55: position slot
    int chalf = rem & 1;
    int n = gq * 8 + res;

    // stage this chalf's 18 weight frags: local lf = tap*2+gg <->
    // global gf = tap*4 + chalf*2 + gg
#pragma unroll
    for (int i = 0; i < 5; ++i) {
        int idx = i * 256 + t;       // 16B-chunk index, 1152 total
        if (idx < 1152) {
            int lf = idx >> 6;
            int lane = idx & 63;
            int gf = (lf >> 1) * 4 + chalf * 2 + (lf & 1);
            *reinterpret_cast<int4*>(wlds + (size_t)idx * 16) =
                *reinterpret_cast<const int4*>(wb + (size_t)(gf * 64 + lane) * 16);
        }
    }
    __syncthreads();

    int wave = t >> 6;
    int lane = t & 63;

    int r = k * 4 + wave;            // 0..223: (h, half) slot
    int h = r >> 1;
    int half = r & 1;
    int w0 = half ? 64 : 0;

    int laneoff = (lane & 15) * 64 + (lane >> 4) * 16;
    const signed char* abase =
        qp + ((size_t)(n * QP_HP + h) * QP_WP + w0) * QP_C + laneoff;
    const signed char* wl = wlds + lane * 16;     // local frag lf at wl + lf*1024
    float* outp = out + (size_t)n * 64 * 12544 + h * 112 + w0;

    if (half == 0)
        conv_tile<4>(abase, wl, bias, deq, outp, lane, chalf * 32);
    else
        conv_tile<3>(abase, wl, bias, deq, outp, lane, chalf * 32);
}

extern "C" void kernel_launch(void* const* d_in, const int* in_sizes, int n_in,
                              void* d_out, int out_size, void* d_ws, size_t ws_size,
                              hipStream_t stream) {
    const float* x   = (const float*)d_in[0];
    const int*   qw  = (const int*)d_in[1];    // int8 values widened to int32
    const int*   bias = (const int*)d_in[2];
    const float* deq = (const float*)d_in[3];
    float* out = (float*)d_out;

    signed char* qp = (signed char*)d_ws;
    signed char* wb = qp + QP_BYTES;

    quantize_kernel<<<QBLOCKS + PBLOCKS, 256, 0, stream>>>(x, qp, qw, wb);
    conv_kernel<<<3584, 256, 0, stream>>>(qp, wb, bias, deq, out);
}

// Round 10
// 56.395 us; speedup vs baseline: 1.2333x; 1.2333x over previous
//
#include <hip/hip_runtime.h>
#include <hip/hip_bf16.h>

typedef int v4i __attribute__((ext_vector_type(4)));

// Padded quantized activations: qp[n][hp][wp][c], hp,wp in [0,114), c in [0,64)
#define QP_N 32
#define QP_HP 114
#define QP_WP 114
#define QP_C 64
#define QP_ROW (QP_WP * QP_C)                            // 7296 B per padded row
#define QP_BYTES ((size_t)QP_N * QP_HP * QP_WP * QP_C)   // 26,615,808

#define QBLOCKS (QP_N * QP_HP)      // 3648 quantize blocks
#define PBLOCKS 9                   // prepack blocks folded into same launch

// XCD pinning: blockIdx round-robins across 8 XCDs. Both kernels remap
// blockIdx bijectively so every block of image n satisfies blockIdx % 8 ==
// n % 8: quantize blocks WRITE image n's qp rows on the same XCD where conv
// blocks READ them. Per-XCD qp working set = 4 images * 832 KB = 3.3 MB <
// 4 MB L2. NO nontemporal hints (r4-r6: NT cost +5-7us every time).

// ---------------------------------------------------------------------------
// Kernel 1: quantize + NCHW -> padded NHWC int8 transpose, with border zeroing.
// Physical blocks [0, 3648): p = ((n>>3)*114 + hp)*8 + (n&7)  (bijective).
// hp==0/113 -> zero row. Else transpose row h=hp-1 through LDS and zero the
// wp=0 / wp=113 columns.
// Blocks [3648, 3657): weight prepack into MFMA B-fragment layout.
//   wb[frag][lane][16B], frag = (kh*3+kw)*4 + g.
//   B-frag (K=ci x N=co): lane l holds B[k=(l>>4)*16+j][n = l&15], j=0..15.
//   co = g*16 + (l&15), ci = (l>>4)*16 + j.  qw arrives widened to int32.
// ---------------------------------------------------------------------------
__global__ __launch_bounds__(256) void quantize_kernel(const float* __restrict__ x,
                                                       signed char* __restrict__ qp,
                                                       const int* __restrict__ qw,
                                                       signed char* __restrict__ wb) {
    int t = threadIdx.x;

    if (blockIdx.x >= QBLOCKS) {
        // ---- prepack path ----
        int idx = (blockIdx.x - QBLOCKS) * 256 + t;
        if (idx >= 36 * 64) return;
        int lane = idx & 63;
        int frag = idx >> 6;             // 0..35
        int g = frag & 3;
        int tap = frag >> 2;             // kh*3+kw
        int kh = tap / 3;
        int kw = tap - kh * 3;
        int co = g * 16 + (lane & 15);
        int cibase = (lane >> 4) * 16;
        int dwv[4];
#pragma unroll
        for (int d = 0; d < 4; ++d) {
            int acc = 0;
#pragma unroll
            for (int b = 0; b < 4; ++b) {
                int ci = cibase + d * 4 + b;
                int v = qw[((co * 64 + ci) * 3 + kh) * 3 + kw];
                acc |= (v & 0xff) << (8 * b);
            }
            dwv[d] = acc;
        }
        *reinterpret_cast<int4*>(wb + (size_t)idx * 16) = make_int4(dwv[0], dwv[1], dwv[2], dwv[3]);
        return;
    }

    // XCD-pinned index decode: p = ((n>>3)*114 + hp)*8 + (n&7)
    int p = blockIdx.x;
    int res = p & 7;
    int r = p >> 3;                 // 0..455
    int gq = r / 114;               // n>>3 in 0..3
    int hp = r - gq * 114;
    int n = gq * 8 + res;

    signed char* rowbase = qp + ((size_t)n * QP_HP + hp) * QP_ROW;

    if (hp == 0 || hp == QP_HP - 1) {
        // zero the whole padded row: 114*64 = 7296 B = 228 * 32B
        if (t < 228) {
            int4 z = make_int4(0, 0, 0, 0);
            int4* dst = reinterpret_cast<int4*>(rowbase + t * 32);
            dst[0] = z;
            dst[1] = z;
        }
        return;
    }

    int h = hp - 1;
    __shared__ float lds[64][112];

    const float* xp = x + (size_t)n * 64 * 12544 + h * 112;  // x[n][c][h][w], c-plane stride 12544
#pragma unroll
    for (int j = 0; j < 7; ++j) {
        int fidx = j * 256 + t;      // 1792 float4 chunks total (64 rows * 28)
        int c = fidx / 28;
        int f = fidx - c * 28;
        float4 v = *reinterpret_cast<const float4*>(xp + (size_t)c * 12544 + f * 4);
        *reinterpret_cast<float4*>(&lds[c][f * 4]) = v;
    }
    __syncthreads();

    if (t < 224) {
        int w = t >> 1;              // 0..111
        int ch = (t & 1) * 32;       // channel half: 0 or 32
        int dw[8];
#pragma unroll
        for (int q = 0; q < 8; ++q) {
            int d = 0;
#pragma unroll
            for (int b = 0; b < 4; ++b) {
                float v = lds[ch + q * 4 + b][w];
                float s = rintf(v * 20.0f);                 // round-half-to-even, matches jnp.round
                s = fminf(127.0f, fmaxf(-128.0f, s));
                int iv = (int)s;
                d |= (iv & 0xff) << (8 * b);
            }
            dw[q] = d;
        }
        int4* dst = reinterpret_cast<int4*>(rowbase + (size_t)(w + 1) * QP_C + ch);
        dst[0] = make_int4(dw[0], dw[1], dw[2], dw[3]);
        dst[1] = make_int4(dw[4], dw[5], dw[6], dw[7]);
    } else if (t < 232) {
        // zero border columns wp=0 and wp=113 (64 B each = 4 int4 each)
        int i = t - 224;
        int col = (i >> 2) ? (QP_WP - 1) : 0;
        int part = i & 3;
        *reinterpret_cast<int4*>(rowbase + (size_t)col * QP_C + part * 16) = make_int4(0, 0, 0, 0);
    }
}

// ---------------------------------------------------------------------------
// Kernel 2: implicit-GEMM conv, A = activations (M=16 px), B = weights (N=16 co).
// r7 structure + ONE-TAP-AHEAD register prefetch (r4 idea de-confounded: no NT,
// no 8-wave, natural 4-wave blocks) + s_setprio around MFMA clusters (waves
// are barrier-free after weight stage -> desynced regime where setprio pays).
// Per tap t: issue tap t+1's 4 A-loads, then ds_read 4 wf + 16 MFMAs on af(t).
// Live regs ~ acc64 + af16 + afn16 + wf16 + addr ~ 124 <= 128 cap (256,4).
//   A-frag: lane l reads qp[n][h+kh][w0+pb*16+kw + (l&15)][(l>>4)*16 ..+16]
//   D-frag (pb,g): co = g*16 + (l&15), pixels (l>>4)*4..+3 -> plain float4
// ---------------------------------------------------------------------------
template <int NPB>
__device__ __forceinline__ void conv_tile(const signed char* __restrict__ abase,
                                          const signed char* wl,
                                          const int* __restrict__ bias,
                                          const float* __restrict__ deq,
                                          float* __restrict__ outp,
                                          int lane) {
    v4i acc[NPB][4];
#pragma unroll
    for (int pb = 0; pb < NPB; ++pb)
#pragma unroll
        for (int g = 0; g < 4; ++g)
            acc[pb][g] = (v4i){0, 0, 0, 0};

    // prologue: tap 0 (kh=0, kw=0) A-fragments
    v4i af[NPB];
#pragma unroll
    for (int pb = 0; pb < NPB; ++pb)
        af[pb] = *reinterpret_cast<const v4i*>(abase + (size_t)(pb * 16) * QP_C);

#pragma unroll
    for (int t = 0; t < 9; ++t) {
        v4i afn[NPB];
        if (t < 8) {
            const int t1 = t + 1;
            const int kh1 = t1 / 3;
            const int kw1 = t1 - kh1 * 3;
            const signed char* arow = abase + (size_t)kh1 * QP_ROW + kw1 * QP_C;
#pragma unroll
            for (int pb = 0; pb < NPB; ++pb)
                afn[pb] = *reinterpret_cast<const v4i*>(arow + (size_t)(pb * 16) * QP_C);
        }
        v4i w0f = *reinterpret_cast<const v4i*>(wl + (size_t)(t * 4 + 0) * 1024);
        v4i w1f = *reinterpret_cast<const v4i*>(wl + (size_t)(t * 4 + 1) * 1024);
        v4i w2f = *reinterpret_cast<const v4i*>(wl + (size_t)(t * 4 + 2) * 1024);
        v4i w3f = *reinterpret_cast<const v4i*>(wl + (size_t)(t * 4 + 3) * 1024);
        __builtin_amdgcn_s_setprio(1);
#pragma unroll
        for (int pb = 0; pb < NPB; ++pb) {
            acc[pb][0] = __builtin_amdgcn_mfma_i32_16x16x64_i8(af[pb], w0f, acc[pb][0], 0, 0, 0);
            acc[pb][1] = __builtin_amdgcn_mfma_i32_16x16x64_i8(af[pb], w1f, acc[pb][1], 0, 0, 0);
            acc[pb][2] = __builtin_amdgcn_mfma_i32_16x16x64_i8(af[pb], w2f, acc[pb][2], 0, 0, 0);
            acc[pb][3] = __builtin_amdgcn_mfma_i32_16x16x64_i8(af[pb], w3f, acc[pb][3], 0, 0, 0);
        }
        __builtin_amdgcn_s_setprio(0);
        if (t < 8) {
#pragma unroll
            for (int pb = 0; pb < NPB; ++pb)
                af[pb] = afn[pb];
        }
    }

    int cbase = lane & 15;           // co within group
    int pq = (lane >> 4) * 4;        // pixel quad start within 16-px block
#pragma unroll
    for (int g = 0; g < 4; ++g) {
        int co = g * 16 + cbase;
        int bv = bias[co];
        float dv = deq[co];
        float* orow = outp + (size_t)co * 12544 + pq;
#pragma unroll
        for (int pb = 0; pb < NPB; ++pb) {
            float4 v;
            v.x = (float)(acc[pb][g][0] + bv) * dv;
            v.y = (float)(acc[pb][g][1] + bv) * dv;
            v.z = (float)(acc[pb][g][2] + bv) * dv;
            v.w = (float)(acc[pb][g][3] + bv) * dv;
            *reinterpret_cast<float4*>(orow + pb * 16) = v;
        }
    }
}

__global__ __launch_bounds__(256, 4) void conv_kernel(const signed char* __restrict__ qp,
                                                      const signed char* __restrict__ wb,
                                                      const int* __restrict__ bias,
                                                      const float* __restrict__ deq,
                                                      float* __restrict__ out) {
    __shared__ signed char wlds[36864];
    int t = threadIdx.x;
#pragma unroll
    for (int i = 0; i < 9; ++i) {
        *reinterpret_cast<int4*>(&wlds[(size_t)(i * 256 + t) * 16]) =
            *reinterpret_cast<const int4*>(wb + (size_t)(i * 256 + t) * 16);
    }
    __syncthreads();

    int wave = t >> 6;
    int lane = t & 63;

    // XCD-pinned index decode: p = ((n>>3)*56 + k)*8 + (n&7), k = block-in-image
    int p = blockIdx.x;              // 0..1791
    int res = p & 7;
    int s = p >> 3;                  // 0..223
    int gq = s / 56;                 // n>>3 in 0..3
    int k = s - gq * 56;             // 0..55
    int n = gq * 8 + res;

    int r = k * 4 + wave;            // 0..223: (h, half) slot
    int h = r >> 1;
    int half = r & 1;
    int w0 = half ? 64 : 0;

    int laneoff = (lane & 15) * 64 + (lane >> 4) * 16;
    const signed char* abase =
        qp + ((size_t)(n * QP_HP + h) * QP_WP + w0) * QP_C + laneoff;
    const signed char* wl = wlds + lane * 16;     // B-frag f at wl + f*1024
    float* outp = out + (size_t)n * 64 * 12544 + h * 112 + w0;

    if (half == 0)
        conv_tile<4>(abase, wl, bias, deq, outp, lane);
    else
        conv_tile<3>(abase, wl, bias, deq, outp, lane);
}

extern "C" void kernel_launch(void* const* d_in, const int* in_sizes, int n_in,
                              void* d_out, int out_size, void* d_ws, size_t ws_size,
                              hipStream_t stream) {
    const float* x   = (const float*)d_in[0];
    const int*   qw  = (const int*)d_in[1];    // int8 values widened to int32
    const int*   bias = (const int*)d_in[2];
    const float* deq = (const float*)d_in[3];
    float* out = (float*)d_out;

    signed char* qp = (signed char*)d_ws;
    signed char* wb = qp + QP_BYTES;

    quantize_kernel<<<QBLOCKS + PBLOCKS, 256, 0, stream>>>(x, qp, qw, wb);
    conv_kernel<<<1792, 256, 0, stream>>>(qp, wb, bias, deq, out);
}